// Round 8
// baseline (581.607 us; speedup 1.0000x reference)
//
#include <hip/hip_runtime.h>

// Problem constants (fixed by setup_inputs)
#define B_ 8
#define T_ 2048
#define C_ 1024
#define H_ 4096
#define E_ 8
#define S_ (2 * T_)          // slots per batch row (K=2)
#define CAP 320              // int(T/E * 1.25)
#define ME 2560              // rows per expert = B_*CAP (20 x 128)
#define NROWS (E_ * ME)      // 20480 bucket rows

typedef __attribute__((ext_vector_type(8))) short short8;
typedef __attribute__((ext_vector_type(4))) float f32x4;
typedef __attribute__((ext_vector_type(16))) float f32x16;

__device__ __forceinline__ unsigned short f2bf(float f) {
  unsigned u = __float_as_uint(f);
  unsigned r = 0x7FFFu + ((u >> 16) & 1u);   // RNE, no NaN in this data
  return (unsigned short)((u + r) >> 16);
}
__device__ __forceinline__ float bf2f(unsigned short u) {
  return __uint_as_float(((unsigned)u) << 16);
}

__device__ __forceinline__ void gload_lds16(const void* g, void* l) {
  __builtin_amdgcn_global_load_lds(
      (const __attribute__((address_space(1))) unsigned int*)g,
      (__attribute__((address_space(3))) unsigned int*)l, 16, 0, 0);
}

// ---------------- weight transpose+convert (W1 and W2 in one launch) -------
// W1: [E][C][H] fp32 -> W1T [E][H][C] bf16 (8192 tiles of 64x64)
// W2: [E][H][C] fp32 -> W2T [E][C][H] bf16 (8192 tiles)
__global__ void cvt_transpose2(const float* __restrict__ W1,
                               const float* __restrict__ W2,
                               unsigned short* __restrict__ W1T,
                               unsigned short* __restrict__ W2T) {
  __shared__ float t[64][65];
  const int tid = threadIdx.x;
  const int bid = blockIdx.x;
  const float* in;
  unsigned short* out;
  int R, Cc, r0, c0;
  long eoff;
  if (bid < 8192) {            // W1: R=1024, Cc=4096; 16 x 64 tiles/expert
    const int tt = bid;
    const int e = tt >> 10;
    const int rt = (tt >> 6) & 15, ct = tt & 63;
    in = W1; out = W1T; R = C_; Cc = H_;
    r0 = rt * 64; c0 = ct * 64;
    eoff = (long)e * C_ * H_;
  } else {                     // W2: R=4096, Cc=1024; 64 x 16 tiles/expert
    const int tt = bid - 8192;
    const int e = tt >> 10;
    const int rt = (tt & 1023) >> 4, ct = tt & 15;
    in = W2; out = W2T; R = H_; Cc = C_;
    r0 = rt * 64; c0 = ct * 64;
    eoff = (long)e * C_ * H_;
  }
#pragma unroll
  for (int it = 0; it < 4; ++it) {
    int r = it * 16 + (tid >> 4);
    int c = (tid & 15) * 4;
    float4 v = *(const float4*)(in + eoff + (long)(r0 + r) * Cc + c0 + c);
    t[r][c] = v.x; t[r][c + 1] = v.y; t[r][c + 2] = v.z; t[r][c + 3] = v.w;
  }
  __syncthreads();
#pragma unroll
  for (int it = 0; it < 4; ++it) {
    int oc = it * 16 + (tid >> 4);   // column index (output row c0+oc)
    int orr = (tid & 15) * 4;        // original rows r0+orr..+3 (output cols)
    union { unsigned short u[4]; unsigned long long ll; } o;
    o.u[0] = f2bf(t[orr + 0][oc]); o.u[1] = f2bf(t[orr + 1][oc]);
    o.u[2] = f2bf(t[orr + 2][oc]); o.u[3] = f2bf(t[orr + 3][oc]);
    *(unsigned long long*)(out + eoff + (long)(c0 + oc) * R + r0 + orr) = o.ll;
  }
}

// ---------------- fused router + x->bf16 convert: one wave per token --------
__global__ void router_cvt(const float* __restrict__ x, const float* __restrict__ Wr,
                           int* __restrict__ es, float* __restrict__ ps,
                           unsigned short* __restrict__ x_bf) {
  const int token = blockIdx.x * 4 + (threadIdx.x >> 6);
  const int lane = threadIdx.x & 63;
  const float* xr = x + (long)token * C_;
  float acc[8] = {0, 0, 0, 0, 0, 0, 0, 0};
#pragma unroll
  for (int j = 0; j < 4; ++j) {
    int c = j * 256 + lane * 4;
    float4 xv = *(const float4*)(xr + c);
    union { unsigned short u[4]; unsigned long long ll; } o;
    o.u[0] = f2bf(xv.x); o.u[1] = f2bf(xv.y); o.u[2] = f2bf(xv.z); o.u[3] = f2bf(xv.w);
    *(unsigned long long*)(x_bf + (long)token * C_ + c) = o.ll;
    const float xe[4] = {xv.x, xv.y, xv.z, xv.w};
#pragma unroll
    for (int i = 0; i < 4; ++i) {
      const float4* wr = (const float4*)(Wr + (long)(c + i) * 8);
      float4 w0 = wr[0], w1 = wr[1];
      float v = xe[i];
      acc[0] += v * w0.x; acc[1] += v * w0.y; acc[2] += v * w0.z; acc[3] += v * w0.w;
      acc[4] += v * w1.x; acc[5] += v * w1.y; acc[6] += v * w1.z; acc[7] += v * w1.w;
    }
  }
#pragma unroll
  for (int off = 32; off >= 1; off >>= 1)
#pragma unroll
    for (int e = 0; e < 8; ++e) acc[e] += __shfl_xor(acc[e], off);
  float mx = acc[0];
#pragma unroll
  for (int e = 1; e < 8; ++e) mx = fmaxf(mx, acc[e]);
  float pr[8], se = 0.f;
#pragma unroll
  for (int e = 0; e < 8; ++e) { pr[e] = expf(acc[e] - mx); se += pr[e]; }
  float inv = 1.f / se;
  // top-2 on probs, jax tie-break: lower index wins on equality (strict >)
  int e0 = 0; float v0 = pr[0];
#pragma unroll
  for (int e = 1; e < 8; ++e) if (pr[e] > v0) { v0 = pr[e]; e0 = e; }
  int e1 = -1; float v1 = -1.f;
#pragma unroll
  for (int e = 0; e < 8; ++e) if (e != e0 && pr[e] > v1) { v1 = pr[e]; e1 = e; }
  if (lane == 0) {
    es[2 * token] = e0;     ps[2 * token] = v0 * inv;
    es[2 * token + 1] = e1; ps[2 * token + 1] = v1 * inv;
  }
}

// ---------------- positions: sequential scan per batch row ----------------
// tsrc[e*ME + b*CAP + pos] = global x row (b*T + t); -1 where bucket empty.
// Tail-fills -1 itself (replaces the separate memset dispatch).
__global__ void positions(const int* __restrict__ es, int* __restrict__ pos,
                          int* __restrict__ tsrc) {
  const int b = blockIdx.x;
  const int lane = threadIdx.x;  // 64 threads
  int cnt[8] = {0, 0, 0, 0, 0, 0, 0, 0};
  unsigned long long below = (1ULL << lane) - 1ULL;
  int e_next = es[(long)b * S_ + lane];
  for (int chunk = 0; chunk < S_ / 64; ++chunk) {
    int e = e_next;
    if (chunk + 1 < S_ / 64) e_next = es[(long)b * S_ + (chunk + 1) * 64 + lane];
    int myPos = 0;
#pragma unroll
    for (int ei = 0; ei < 8; ++ei) {
      unsigned long long m = __ballot(e == ei);
      if (e == ei) myPos = cnt[ei] + __popcll(m & below);
      cnt[ei] += __popcll(m);
    }
    int s = chunk * 64 + lane;
    pos[(long)b * S_ + s] = myPos;
    if (myPos < CAP)
      tsrc[(long)e * ME + b * CAP + myPos] = b * T_ + (s >> 1);
  }
  // tail fill: slots beyond the bucket's fill get -1 (cnt is wave-uniform)
#pragma unroll
  for (int ei = 0; ei < 8; ++ei)
    for (int p = cnt[ei] + lane; p < CAP; p += 64)
      tsrc[(long)ei * ME + b * CAP + p] = -1;
}

// ---------------- grouped MFMA GEMM, m97 structure, 32x32x16 MFMA ----------
// Same verified staging/swizzle/barrier structure as rounds 3/7 (834-840 TF,
// 0 bank conflicts); only the MFMA shape changes: 16x16x32 -> 32x32x16
// (8.07 cyc per 32k FLOP vs 9.7 -- 17% less matrix-pipe time, half the MFMA
// instruction count). Per-wave 64x64 out = 2x2 tiles of 32x32, acc 4 x f32x16
// (64 VGPRs, unchanged). LDS read volume unchanged (16 b128/wave/K-tile,
// exactly 8 accesses/bank under the same involution swizzle).
// A-frag assumed mapping (symmetric w/ verified 16x16x32): row=lane&31,
// k=(lane>>5)*8+j. C/D mapping HW-verified [m74/m101]: col=lane&31,
// row=(reg&3)+8*(reg>>2)+4*(lane>>5).
template <bool GATHER, bool RELU>
__global__ __launch_bounds__(256, 3) void moe_gemm(
    const unsigned short* __restrict__ A, const unsigned short* __restrict__ BT,
    const float* __restrict__ bias, const int* __restrict__ tsrc,
    unsigned short* __restrict__ outp, const int Kdim, const int N, const int NT) {
  constexpr int BM = 128, BN = 128, BK = 64;
  constexpr int MT = ME / BM;  // 20
  __shared__ unsigned short As[BM * BK];  // 16 KB, XOR-swizzled 16B slots
  __shared__ unsigned short Bs[BN * BK];  // 16 KB
  const int tid = threadIdx.x, lane = tid & 63, w = tid >> 6;

  // XCD-aware swizzle: grid = E_*NT*MT, always divisible by 8.
  const int nwg = E_ * NT * MT;
  const int chunk = nwg >> 3;
  const int swz = (blockIdx.x & 7) * chunk + (blockIdx.x >> 3);
  const int e = swz / (NT * MT);
  const int rem = swz % (NT * MT);
  const int nt = rem / MT, mt = rem % MT;
  const int n0 = nt * BN;

  // staging: wave w covers A rows [w*32,w*32+32) in 4 issues of 8 rows; same B.
  // LDS linear dest + pre-swizzled global source slot (j ^ (row&7)) so the
  // swizzled ds_read below is the matching involution (guide rule #21).
  const unsigned short* aPtr[4];
#pragma unroll
  for (int i = 0; i < 4; ++i) {
    int ra = w * 32 + i * 8 + (lane >> 3);
    int j = lane & 7;
    long rowbase;
    if constexpr (GATHER) {
      int xrow = tsrc[(long)e * ME + mt * BM + ra];
      if (xrow < 0) xrow = 0;  // empty bucket row: garbage, never gathered back
      rowbase = (long)xrow * Kdim;
    } else {
      rowbase = ((long)e * ME + mt * BM + ra) * (long)Kdim;
    }
    aPtr[i] = A + rowbase + ((j ^ (ra & 7)) << 3);
  }
  const unsigned short* bPtr[4];
#pragma unroll
  for (int i = 0; i < 4; ++i) {
    int rb = w * 32 + i * 8 + (lane >> 3);
    int j = lane & 7;
    bPtr[i] = BT + ((long)e * N + n0 + rb) * (long)Kdim + ((j ^ (rb & 7)) << 3);
  }

  const int wm = w >> 1, wn = w & 1;   // 2x2 waves, each 64x64 output
  f32x16 acc[2][2];
#pragma unroll
  for (int mi = 0; mi < 2; ++mi)
#pragma unroll
    for (int ni = 0; ni < 2; ++ni)
#pragma unroll
      for (int r = 0; r < 16; ++r) acc[mi][ni][r] = 0.f;

  const int l31 = lane & 31, l5 = lane >> 5;
  const int sxor = l31 & 7;  // row&7 for frag reads (tile bases are %32==0)

  for (int kt = 0; kt < Kdim / BK; ++kt) {
#pragma unroll
    for (int i = 0; i < 4; ++i)
      gload_lds16(aPtr[i], &As[(w * 32 + i * 8) * BK]);
#pragma unroll
    for (int i = 0; i < 4; ++i)
      gload_lds16(bPtr[i], &Bs[(w * 32 + i * 8) * BK]);
#pragma unroll
    for (int i = 0; i < 4; ++i) { aPtr[i] += BK; bPtr[i] += BK; }
    __syncthreads();
#pragma unroll
    for (int s = 0; s < 2; ++s) {
      short8 af[2][2], bf[2][2];  // [tile][k2]
#pragma unroll
      for (int mi = 0; mi < 2; ++mi)
#pragma unroll
        for (int k2 = 0; k2 < 2; ++k2) {
          int row = wm * 64 + mi * 32 + l31;
          int slot = ((s * 2 + k2) * 2 + l5) ^ sxor;
          af[mi][k2] = *(const short8*)&As[row * BK + slot * 8];
        }
#pragma unroll
      for (int ni = 0; ni < 2; ++ni)
#pragma unroll
        for (int k2 = 0; k2 < 2; ++k2) {
          int row = wn * 64 + ni * 32 + l31;
          int slot = ((s * 2 + k2) * 2 + l5) ^ sxor;
          bf[ni][k2] = *(const short8*)&Bs[row * BK + slot * 8];
        }
#pragma unroll
      for (int mi = 0; mi < 2; ++mi)
#pragma unroll
        for (int ni = 0; ni < 2; ++ni)
#pragma unroll
          for (int k2 = 0; k2 < 2; ++k2)
            acc[mi][ni] = __builtin_amdgcn_mfma_f32_32x32x16_bf16(
                af[mi][k2], bf[ni][k2], acc[mi][ni], 0, 0, 0);
    }
    __syncthreads();
  }

  // epilogue: C/D layout col=lane&31, row=(reg&3)+8*(reg>>2)+4*(lane>>5) [m74]
  const long rbase = (long)e * ME + mt * BM;
#pragma unroll
  for (int mi = 0; mi < 2; ++mi) {
#pragma unroll
    for (int ni = 0; ni < 2; ++ni) {
      const int col = n0 + wn * 64 + ni * 32 + l31;
      const float bv = bias[(long)e * N + col];
      const long rowb = rbase + wm * 64 + mi * 32 + 4 * l5;
#pragma unroll
      for (int r = 0; r < 16; ++r) {
        const int rrow = (r & 3) + 8 * (r >> 2);
        float v = acc[mi][ni][r] + bv;
        if constexpr (RELU) v = fmaxf(v, 0.f);
        outp[(rowb + rrow) * N + col] = f2bf(v);
      }
    }
  }
}

// ---------------- combine (y in bf16) ----------------
__global__ void combine(const unsigned short* __restrict__ y,
                        const int* __restrict__ es, const float* __restrict__ ps,
                        const int* __restrict__ pos, float* __restrict__ out) {
  const int token = blockIdx.x;  // b*T + t
  const int b = token >> 11;     // T = 2048
  const int s0 = 2 * token, s1 = s0 + 1;
  int e0 = es[s0], e1 = es[s1];
  int q0 = pos[s0], q1 = pos[s1];
  float p0 = ps[s0], p1 = ps[s1];
  const bool k0 = q0 < CAP, k1 = q1 < CAP;
  if (q0 > CAP - 1) q0 = CAP - 1;
  if (q1 > CAP - 1) q1 = CAP - 1;
  const unsigned short* r0 = y + ((long)e0 * ME + b * CAP + q0) * C_;
  const unsigned short* r1 = y + ((long)e1 * ME + b * CAP + q1) * C_;
  const int c = threadIdx.x * 4;  // 256 threads x 4 cols
  float4 a = {0.f, 0.f, 0.f, 0.f};
  if (k0) {
    union { unsigned short u[4]; unsigned long long ll; } v;
    v.ll = *(const unsigned long long*)(r0 + c);
    a.x += p0 * bf2f(v.u[0]); a.y += p0 * bf2f(v.u[1]);
    a.z += p0 * bf2f(v.u[2]); a.w += p0 * bf2f(v.u[3]);
  }
  if (k1) {
    union { unsigned short u[4]; unsigned long long ll; } v;
    v.ll = *(const unsigned long long*)(r1 + c);
    a.x += p1 * bf2f(v.u[0]); a.y += p1 * bf2f(v.u[1]);
    a.z += p1 * bf2f(v.u[2]); a.w += p1 * bf2f(v.u[3]);
  }
  *(float4*)(out + (long)token * C_ + c) = a;
}

// ---------------- launch ----------------
extern "C" void kernel_launch(void* const* d_in, const int* in_sizes, int n_in,
                              void* d_out, int out_size, void* d_ws, size_t ws_size,
                              hipStream_t stream) {
  const float* x = (const float*)d_in[0];
  const float* Wr = (const float*)d_in[1];
  const float* W1 = (const float*)d_in[2];
  const float* b1 = (const float*)d_in[3];
  const float* W2 = (const float*)d_in[4];
  const float* b2 = (const float*)d_in[5];
  float* out = (float*)d_out;
  char* ws = (char*)d_ws;
  // workspace layout (~378 MB)
  unsigned short* x_bf = (unsigned short*)(ws + 0L);          // 33,554,432
  unsigned short* W1T = (unsigned short*)(ws + 33554432L);    // 67,108,864  [E][H][C]
  unsigned short* W2T = (unsigned short*)(ws + 100663296L);   // 67,108,864  [E][C][H]
  unsigned short* h = (unsigned short*)(ws + 167772160L);     // 167,772,160 [NROWS][H]
  unsigned short* y = (unsigned short*)(ws + 335544320L);     // 41,943,040  [NROWS][C] bf16
  int* es = (int*)(ws + 377487360L);                          // 131,072
  float* ps = (float*)(ws + 377618432L);                      // 131,072
  int* pos = (int*)(ws + 377749504L);                         // 131,072
  int* tsrc = (int*)(ws + 377880576L);                        // 81,920

  cvt_transpose2<<<16384, 256, 0, stream>>>(W1, W2, W1T, W2T);
  router_cvt<<<4096, 256, 0, stream>>>(x, Wr, es, ps, x_bf);
  positions<<<8, 64, 0, stream>>>(es, pos, tsrc);
  // GEMM1: per-expert M=2560, N=4096 (NT=32): grid 8*32*20 = 5120
  moe_gemm<true, true><<<5120, 256, 0, stream>>>(x_bf, W1T, b1, tsrc, h, C_, H_, 32);
  // GEMM2: N=1024 (NT=8): grid 8*8*20 = 1280
  moe_gemm<false, false><<<1280, 256, 0, stream>>>(h, W2T, b2, nullptr, y, H_, C_, 8);
  combine<<<16384, 256, 0, stream>>>(y, es, ps, pos, out);
}

// Round 9
// 559.682 us; speedup vs baseline: 1.0392x; 1.0392x over previous
//
#include <hip/hip_runtime.h>

// Problem constants (fixed by setup_inputs)
#define B_ 8
#define T_ 2048
#define C_ 1024
#define H_ 4096
#define E_ 8
#define S_ (2 * T_)          // slots per batch row (K=2)
#define CAP 320              // int(T/E * 1.25)
#define ME 2560              // rows per expert = B_*CAP (20 x 128)
#define NROWS (E_ * ME)      // 20480 bucket rows

typedef __attribute__((ext_vector_type(8))) short short8;
typedef __attribute__((ext_vector_type(4))) float f32x4;

__device__ __forceinline__ unsigned short f2bf(float f) {
  unsigned u = __float_as_uint(f);
  unsigned r = 0x7FFFu + ((u >> 16) & 1u);   // RNE, no NaN in this data
  return (unsigned short)((u + r) >> 16);
}
__device__ __forceinline__ float bf2f(unsigned short u) {
  return __uint_as_float(((unsigned)u) << 16);
}

__device__ __forceinline__ void gload_lds16(const void* g, void* l) {
  __builtin_amdgcn_global_load_lds(
      (const __attribute__((address_space(1))) unsigned int*)g,
      (__attribute__((address_space(3))) unsigned int*)l, 16, 0, 0);
}

// ---------------- weight transpose+convert (W1 and W2 in one launch) -------
// W1: [E][C][H] fp32 -> W1T [E][H][C] bf16 (8192 tiles of 64x64)
// W2: [E][H][C] fp32 -> W2T [E][C][H] bf16 (8192 tiles)
__global__ void cvt_transpose2(const float* __restrict__ W1,
                               const float* __restrict__ W2,
                               unsigned short* __restrict__ W1T,
                               unsigned short* __restrict__ W2T) {
  __shared__ float t[64][65];
  const int tid = threadIdx.x;
  const int bid = blockIdx.x;
  const float* in;
  unsigned short* out;
  int R, Cc, r0, c0;
  long eoff;
  if (bid < 8192) {            // W1: R=1024, Cc=4096; 16 x 64 tiles/expert
    const int tt = bid;
    const int e = tt >> 10;
    const int rt = (tt >> 6) & 15, ct = tt & 63;
    in = W1; out = W1T; R = C_; Cc = H_;
    r0 = rt * 64; c0 = ct * 64;
    eoff = (long)e * C_ * H_;
  } else {                     // W2: R=4096, Cc=1024; 64 x 16 tiles/expert
    const int tt = bid - 8192;
    const int e = tt >> 10;
    const int rt = (tt & 1023) >> 4, ct = tt & 15;
    in = W2; out = W2T; R = H_; Cc = C_;
    r0 = rt * 64; c0 = ct * 64;
    eoff = (long)e * C_ * H_;
  }
#pragma unroll
  for (int it = 0; it < 4; ++it) {
    int r = it * 16 + (tid >> 4);
    int c = (tid & 15) * 4;
    float4 v = *(const float4*)(in + eoff + (long)(r0 + r) * Cc + c0 + c);
    t[r][c] = v.x; t[r][c + 1] = v.y; t[r][c + 2] = v.z; t[r][c + 3] = v.w;
  }
  __syncthreads();
#pragma unroll
  for (int it = 0; it < 4; ++it) {
    int oc = it * 16 + (tid >> 4);   // column index (output row c0+oc)
    int orr = (tid & 15) * 4;        // original rows r0+orr..+3 (output cols)
    union { unsigned short u[4]; unsigned long long ll; } o;
    o.u[0] = f2bf(t[orr + 0][oc]); o.u[1] = f2bf(t[orr + 1][oc]);
    o.u[2] = f2bf(t[orr + 2][oc]); o.u[3] = f2bf(t[orr + 3][oc]);
    *(unsigned long long*)(out + eoff + (long)(c0 + oc) * R + r0 + orr) = o.ll;
  }
}

// ---------------- fused router + x->bf16 convert: one wave per token --------
__global__ void router_cvt(const float* __restrict__ x, const float* __restrict__ Wr,
                           int* __restrict__ es, float* __restrict__ ps,
                           unsigned short* __restrict__ x_bf) {
  const int token = blockIdx.x * 4 + (threadIdx.x >> 6);
  const int lane = threadIdx.x & 63;
  const float* xr = x + (long)token * C_;
  float acc[8] = {0, 0, 0, 0, 0, 0, 0, 0};
#pragma unroll
  for (int j = 0; j < 4; ++j) {
    int c = j * 256 + lane * 4;
    float4 xv = *(const float4*)(xr + c);
    union { unsigned short u[4]; unsigned long long ll; } o;
    o.u[0] = f2bf(xv.x); o.u[1] = f2bf(xv.y); o.u[2] = f2bf(xv.z); o.u[3] = f2bf(xv.w);
    *(unsigned long long*)(x_bf + (long)token * C_ + c) = o.ll;
    const float xe[4] = {xv.x, xv.y, xv.z, xv.w};
#pragma unroll
    for (int i = 0; i < 4; ++i) {
      const float4* wr = (const float4*)(Wr + (long)(c + i) * 8);
      float4 w0 = wr[0], w1 = wr[1];
      float v = xe[i];
      acc[0] += v * w0.x; acc[1] += v * w0.y; acc[2] += v * w0.z; acc[3] += v * w0.w;
      acc[4] += v * w1.x; acc[5] += v * w1.y; acc[6] += v * w1.z; acc[7] += v * w1.w;
    }
  }
#pragma unroll
  for (int off = 32; off >= 1; off >>= 1)
#pragma unroll
    for (int e = 0; e < 8; ++e) acc[e] += __shfl_xor(acc[e], off);
  float mx = acc[0];
#pragma unroll
  for (int e = 1; e < 8; ++e) mx = fmaxf(mx, acc[e]);
  float pr[8], se = 0.f;
#pragma unroll
  for (int e = 0; e < 8; ++e) { pr[e] = expf(acc[e] - mx); se += pr[e]; }
  float inv = 1.f / se;
  // top-2 on probs, jax tie-break: lower index wins on equality (strict >)
  int e0 = 0; float v0 = pr[0];
#pragma unroll
  for (int e = 1; e < 8; ++e) if (pr[e] > v0) { v0 = pr[e]; e0 = e; }
  int e1 = -1; float v1 = -1.f;
#pragma unroll
  for (int e = 0; e < 8; ++e) if (e != e0 && pr[e] > v1) { v1 = pr[e]; e1 = e; }
  if (lane == 0) {
    es[2 * token] = e0;     ps[2 * token] = v0 * inv;
    es[2 * token + 1] = e1; ps[2 * token + 1] = v1 * inv;
  }
}

// ---------------- positions: sequential scan per batch row ----------------
// tsrc[e*ME + b*CAP + pos] = global x row (b*T + t); -1 where bucket empty.
// Tail-fills -1 itself (replaces the separate memset dispatch).
__global__ void positions(const int* __restrict__ es, int* __restrict__ pos,
                          int* __restrict__ tsrc) {
  const int b = blockIdx.x;
  const int lane = threadIdx.x;  // 64 threads
  int cnt[8] = {0, 0, 0, 0, 0, 0, 0, 0};
  unsigned long long below = (1ULL << lane) - 1ULL;
  int e_next = es[(long)b * S_ + lane];
  for (int chunk = 0; chunk < S_ / 64; ++chunk) {
    int e = e_next;
    if (chunk + 1 < S_ / 64) e_next = es[(long)b * S_ + (chunk + 1) * 64 + lane];
    int myPos = 0;
#pragma unroll
    for (int ei = 0; ei < 8; ++ei) {
      unsigned long long m = __ballot(e == ei);
      if (e == ei) myPos = cnt[ei] + __popcll(m & below);
      cnt[ei] += __popcll(m);
    }
    int s = chunk * 64 + lane;
    pos[(long)b * S_ + s] = myPos;
    if (myPos < CAP)
      tsrc[(long)e * ME + b * CAP + myPos] = b * T_ + (s >> 1);
  }
  // tail fill: slots beyond the bucket's fill get -1 (cnt is wave-uniform)
#pragma unroll
  for (int ei = 0; ei < 8; ++ei)
    for (int p = cnt[ei] + lane; p < CAP; p += 64)
      tsrc[(long)ei * ME + b * CAP + p] = -1;
}

// ---------------- grouped MFMA GEMM, m97 structure (128x128 tile) ----------
// Verified-best across 8 rounds: 834-840 TF eff (99% of m248's 848 TF
// plain-HIP grouped reference), MfmaUtil 36%, 0 bank conflicts.
// Rejected by measurement: BM=256 8-phase ports (R4-R6), 32x32x16 MFMA (R8:
// 4-way LDS bank conflict structural to 32-row fragment reads at b128).
// Per-expert M space = ME (2560) contiguous rows. 1D grid, XCD-chunked so each
// XCD owns one expert; mt fastest -> B-panel L2 reuse x20.
// __launch_bounds__(256,3): >=3 waves/SIMD (R2->R3 lifted MfmaUtil 26.6->35.7).
template <bool GATHER, bool RELU>
__global__ __launch_bounds__(256, 3) void moe_gemm(
    const unsigned short* __restrict__ A, const unsigned short* __restrict__ BT,
    const float* __restrict__ bias, const int* __restrict__ tsrc,
    unsigned short* __restrict__ outp, const int Kdim, const int N, const int NT) {
  constexpr int BM = 128, BN = 128, BK = 64;
  constexpr int MT = ME / BM;  // 20
  __shared__ unsigned short As[BM * BK];  // 16 KB, XOR-swizzled 16B slots
  __shared__ unsigned short Bs[BN * BK];  // 16 KB
  const int tid = threadIdx.x, lane = tid & 63, w = tid >> 6;

  // XCD-aware swizzle: grid = E_*NT*MT, always divisible by 8.
  const int nwg = E_ * NT * MT;
  const int chunk = nwg >> 3;
  const int swz = (blockIdx.x & 7) * chunk + (blockIdx.x >> 3);
  const int e = swz / (NT * MT);
  const int rem = swz % (NT * MT);
  const int nt = rem / MT, mt = rem % MT;
  const int n0 = nt * BN;

  // staging: wave w covers A rows [w*32,w*32+32) in 4 issues of 8 rows; same B.
  // LDS linear dest + pre-swizzled global source slot (j ^ (row&7)) so the
  // swizzled ds_read below is the matching involution (guide rule #21).
  const unsigned short* aPtr[4];
#pragma unroll
  for (int i = 0; i < 4; ++i) {
    int ra = w * 32 + i * 8 + (lane >> 3);
    int j = lane & 7;
    long rowbase;
    if constexpr (GATHER) {
      int xrow = tsrc[(long)e * ME + mt * BM + ra];
      if (xrow < 0) xrow = 0;  // empty bucket row: garbage, never gathered back
      rowbase = (long)xrow * Kdim;
    } else {
      rowbase = ((long)e * ME + mt * BM + ra) * (long)Kdim;
    }
    aPtr[i] = A + rowbase + ((j ^ (ra & 7)) << 3);
  }
  const unsigned short* bPtr[4];
#pragma unroll
  for (int i = 0; i < 4; ++i) {
    int rb = w * 32 + i * 8 + (lane >> 3);
    int j = lane & 7;
    bPtr[i] = BT + ((long)e * N + n0 + rb) * (long)Kdim + ((j ^ (rb & 7)) << 3);
  }

  const int wm = w >> 1, wn = w & 1;   // 2x2 waves, each 64x64 output
  f32x4 acc[4][4];
#pragma unroll
  for (int m = 0; m < 4; ++m)
#pragma unroll
    for (int n = 0; n < 4; ++n) acc[m][n] = (f32x4){0.f, 0.f, 0.f, 0.f};

  int arow[4], brow[4];
#pragma unroll
  for (int i = 0; i < 4; ++i) {
    arow[i] = wm * 64 + i * 16 + (lane & 15);
    brow[i] = wn * 64 + i * 16 + (lane & 15);
  }
  const int jjb = lane >> 4;

  for (int kt = 0; kt < Kdim / BK; ++kt) {
#pragma unroll
    for (int i = 0; i < 4; ++i)
      gload_lds16(aPtr[i], &As[(w * 32 + i * 8) * BK]);
#pragma unroll
    for (int i = 0; i < 4; ++i)
      gload_lds16(bPtr[i], &Bs[(w * 32 + i * 8) * BK]);
#pragma unroll
    for (int i = 0; i < 4; ++i) { aPtr[i] += BK; bPtr[i] += BK; }
    __syncthreads();
#pragma unroll
    for (int s = 0; s < 2; ++s) {
      short8 af[4], bf[4];
#pragma unroll
      for (int m = 0; m < 4; ++m) {
        int slot = (s * 4 + jjb) ^ (arow[m] & 7);
        af[m] = *(const short8*)&As[arow[m] * BK + slot * 8];
      }
#pragma unroll
      for (int n = 0; n < 4; ++n) {
        int slot = (s * 4 + jjb) ^ (brow[n] & 7);
        bf[n] = *(const short8*)&Bs[brow[n] * BK + slot * 8];
      }
#pragma unroll
      for (int m = 0; m < 4; ++m)
#pragma unroll
        for (int n = 0; n < 4; ++n)
          acc[m][n] = __builtin_amdgcn_mfma_f32_16x16x32_bf16(af[m], bf[n],
                                                              acc[m][n], 0, 0, 0);
    }
    __syncthreads();
  }

  // epilogue: C/D layout col=lane&15, row=(lane>>4)*4+j  [m89]
  const long rbase = (long)e * ME + mt * BM;
#pragma unroll
  for (int m = 0; m < 4; ++m) {
#pragma unroll
    for (int n = 0; n < 4; ++n) {
      const int trow = wm * 64 + m * 16 + ((lane >> 4) << 2);
      const int col = n0 + wn * 64 + n * 16 + (lane & 15);
      const float bv = bias[(long)e * N + col];
#pragma unroll
      for (int j = 0; j < 4; ++j) {
        float v = acc[m][n][j] + bv;
        if constexpr (RELU) v = fmaxf(v, 0.f);
        outp[(rbase + trow + j) * N + col] = f2bf(v);
      }
    }
  }
}

// ---------------- combine (y in bf16) ----------------
__global__ void combine(const unsigned short* __restrict__ y,
                        const int* __restrict__ es, const float* __restrict__ ps,
                        const int* __restrict__ pos, float* __restrict__ out) {
  const int token = blockIdx.x;  // b*T + t
  const int b = token >> 11;     // T = 2048
  const int s0 = 2 * token, s1 = s0 + 1;
  int e0 = es[s0], e1 = es[s1];
  int q0 = pos[s0], q1 = pos[s1];
  float p0 = ps[s0], p1 = ps[s1];
  const bool k0 = q0 < CAP, k1 = q1 < CAP;
  if (q0 > CAP - 1) q0 = CAP - 1;
  if (q1 > CAP - 1) q1 = CAP - 1;
  const unsigned short* r0 = y + ((long)e0 * ME + b * CAP + q0) * C_;
  const unsigned short* r1 = y + ((long)e1 * ME + b * CAP + q1) * C_;
  const int c = threadIdx.x * 4;  // 256 threads x 4 cols
  float4 a = {0.f, 0.f, 0.f, 0.f};
  if (k0) {
    union { unsigned short u[4]; unsigned long long ll; } v;
    v.ll = *(const unsigned long long*)(r0 + c);
    a.x += p0 * bf2f(v.u[0]); a.y += p0 * bf2f(v.u[1]);
    a.z += p0 * bf2f(v.u[2]); a.w += p0 * bf2f(v.u[3]);
  }
  if (k1) {
    union { unsigned short u[4]; unsigned long long ll; } v;
    v.ll = *(const unsigned long long*)(r1 + c);
    a.x += p1 * bf2f(v.u[0]); a.y += p1 * bf2f(v.u[1]);
    a.z += p1 * bf2f(v.u[2]); a.w += p1 * bf2f(v.u[3]);
  }
  *(float4*)(out + (long)token * C_ + c) = a;
}

// ---------------- launch ----------------
extern "C" void kernel_launch(void* const* d_in, const int* in_sizes, int n_in,
                              void* d_out, int out_size, void* d_ws, size_t ws_size,
                              hipStream_t stream) {
  const float* x = (const float*)d_in[0];
  const float* Wr = (const float*)d_in[1];
  const float* W1 = (const float*)d_in[2];
  const float* b1 = (const float*)d_in[3];
  const float* W2 = (const float*)d_in[4];
  const float* b2 = (const float*)d_in[5];
  float* out = (float*)d_out;
  char* ws = (char*)d_ws;
  // workspace layout (~378 MB)
  unsigned short* x_bf = (unsigned short*)(ws + 0L);          // 33,554,432
  unsigned short* W1T = (unsigned short*)(ws + 33554432L);    // 67,108,864  [E][H][C]
  unsigned short* W2T = (unsigned short*)(ws + 100663296L);   // 67,108,864  [E][C][H]
  unsigned short* h = (unsigned short*)(ws + 167772160L);     // 167,772,160 [NROWS][H]
  unsigned short* y = (unsigned short*)(ws + 335544320L);     // 41,943,040  [NROWS][C] bf16
  int* es = (int*)(ws + 377487360L);                          // 131,072
  float* ps = (float*)(ws + 377618432L);                      // 131,072
  int* pos = (int*)(ws + 377749504L);                         // 131,072
  int* tsrc = (int*)(ws + 377880576L);                        // 81,920

  cvt_transpose2<<<16384, 256, 0, stream>>>(W1, W2, W1T, W2T);
  router_cvt<<<4096, 256, 0, stream>>>(x, Wr, es, ps, x_bf);
  positions<<<8, 64, 0, stream>>>(es, pos, tsrc);
  // GEMM1: per-expert M=2560, N=4096 (NT=32): grid 8*32*20 = 5120
  moe_gemm<true, true><<<5120, 256, 0, stream>>>(x_bf, W1T, b1, tsrc, h, C_, H_, 32);
  // GEMM2: N=1024 (NT=8): grid 8*8*20 = 1280
  moe_gemm<false, false><<<1280, 256, 0, stream>>>(h, W2T, b2, nullptr, y, H_, C_, 8);
  combine<<<16384, 256, 0, stream>>>(y, es, ps, pos, out);
}